// Round 6
// baseline (687.685 us; speedup 1.0000x reference)
//
#include <hip/hip_runtime.h>
#include <hip/hip_bf16.h>
#include <math.h>

typedef unsigned int u32;
typedef unsigned long long u64;
typedef unsigned short u16;
typedef __bf16 bf16x8 __attribute__((ext_vector_type(8)));
typedef float f32x4 __attribute__((ext_vector_type(4)));

#define DEV __device__ __forceinline__

DEV u32 bfr(float f){ u32 u = __float_as_uint(f); return (u + 0x7fffu + ((u>>16)&1u)) >> 16; }
DEV float bfl(u32 w){ return __uint_as_float(w << 16); }
DEV float bfh(u32 w){ return __uint_as_float(w & 0xffff0000u); }
DEV float red32(float v){
  v += __shfl_xor(v,1); v += __shfl_xor(v,2); v += __shfl_xor(v,4);
  v += __shfl_xor(v,8); v += __shfl_xor(v,16); return v;
}

// ---------------- init: slots = mu + exp(ls)*noise ----------------
__global__ void kInitSlots(const float* __restrict__ noise, const float* __restrict__ mu,
                           const float* __restrict__ ls, float* __restrict__ slots){
  int i4 = blockIdx.x*256 + threadIdx.x;   // float4 idx, 0..16383
  int d4 = i4 & 31;
  float4 nv = ((const float4*)noise)[i4];
  float4 mv = ((const float4*)mu)[d4];
  float4 lv = ((const float4*)ls)[d4];
  float4 r;
  r.x = mv.x + expf(lv.x)*nv.x;
  r.y = mv.y + expf(lv.y)*nv.y;
  r.z = mv.z + expf(lv.z)*nv.z;
  r.w = mv.w + expf(lv.w)*nv.w;
  ((float4*)slots)[i4] = r;
}

// ---------------- init: Wg = [Wk;Wv]*g (bf16), c1 = sum g*W, c2 = sum b*W ----------------
__global__ void kInitW(const float* __restrict__ Wk, const float* __restrict__ Wv,
                       const float* __restrict__ g, const float* __restrict__ bb,
                       u16* __restrict__ wg, float* __restrict__ c1, float* __restrict__ c2){
  int e = threadIdx.x;  // 0..255
  const float4* src = (const float4*)((e < 128) ? (Wk + e*128) : (Wv + (e-128)*128));
  float a1 = 0.f, a2 = 0.f;
  #pragma unroll
  for (int d4 = 0; d4 < 32; ++d4){
    float4 wv = src[d4];
    float4 gv = ((const float4*)g)[d4];
    float4 bv = ((const float4*)bb)[d4];
    a1 += wv.x*gv.x + wv.y*gv.y + wv.z*gv.z + wv.w*gv.w;
    a2 += wv.x*bv.x + wv.y*bv.y + wv.z*bv.z + wv.w*bv.w;
    u32 w0 = bfr(wv.x*gv.x) | (bfr(wv.y*gv.y) << 16);
    u32 w1 = bfr(wv.z*gv.z) | (bfr(wv.w*gv.w) << 16);
    *(uint2*)&wg[e*128 + d4*4] = make_uint2(w0, w1);
  }
  c1[e] = a1; c2[e] = a2;
}

// ---------------- init: transposed weight packs for kC ----------------
__global__ void kInitT(const float* __restrict__ Wih, const float* __restrict__ Whh,
                       const float* __restrict__ W1, const float* __restrict__ W2,
                       float2* __restrict__ gruT, float* __restrict__ w1T, float* __restrict__ w2T){
  int i = blockIdx.x*256 + threadIdx.x;
  if (i < 49152){
    int d = i / 384, g = i - d*384;
    gruT[i] = make_float2(Wih[g*128 + d], Whh[g*128 + d]);
  } else if (i < 81920){
    int j = i - 49152;
    int d = j >> 8, h = j & 255;
    w1T[j] = W1[h*128 + d];
  } else if (i < 114688){
    int q = i - 81920;
    int j = q >> 7, d = q & 127;
    w2T[q] = W2[d*256 + j];
  }
}

// ---------------- kernel A: fused-LN K/V projection via bf16 MFMA ----------------
// Restructured for occupancy (2 blocks/CU, 4 waves/SIMD) + short chains:
//  - A-fragments loaded DIRECTLY from global f32 x (no LDS staging, no barrier):
//    lane l -> row l&15, granule kt*4+(l>>4); per-row 128 B contiguous spans.
//  - Row stats: lane-local 32-elem sum + 2 shfl_xor (16, 32).
//  - Each block computes K-half OR V-half of columns (sWg 32 KB).
//  - blockIdx remap: K/V blocks of the same 1024-row slab land on the same XCD
//    (presumed bid%8 round-robin) so the second x read hits that XCD's L2.
//  - Wave-private 16-row epilogue repack (4 KB/wave) -> 1 KB coalesced stores.
__global__ __launch_bounds__(512, 4) void kA(const float* __restrict__ x,
    const u16* __restrict__ wg, const float* __restrict__ c1g, const float* __restrict__ c2g,
    u16* __restrict__ kbuf, u16* __restrict__ vbuf)
{
  __shared__ __align__(16) u16 sWg[128*128];     // 32 KB: this half's Wg rows
  __shared__ __align__(16) u16 sE[8*16*128];     // 32 KB: per-wave epilogue buffers
  __shared__ float sMR[8*32];                    // per-wave mean/rstd (16 rows each)
  __shared__ float sC1[128], sC2[128];
  const int t = threadIdx.x, l = t & 63, w = t >> 6;
  const int bid = blockIdx.x;
  const int half = (bid >> 3) & 1;                       // 0 = K cols, 1 = V cols
  const int rowgroup = (bid & 7)*32 + (bid >> 4);        // 0..255
  const int rowbase = rowgroup * 1024;

  // stage this half's Wg rows (swizzled 16B granules: g' = g ^ (row&7))
  const uint4* wg4 = (const uint4*)wg;
  #pragma unroll
  for (int p = 0; p < 4; ++p){
    int G = t + p*512;            // 0..2047 (128 rows x 16 granules)
    int row = G >> 4, g = G & 15;
    uint4 v = wg4[(half*128 + row)*16 + g];
    *(uint4*)&sWg[row*128 + ((g ^ (row & 7)) << 3)] = v;
  }
  if (t < 128){ sC1[t] = c1g[half*128 + t]; sC2[t] = c2g[half*128 + t]; }
  __syncthreads();   // the ONLY barrier

  u16* dstbuf = half ? vbuf : kbuf;
  const float4* x4 = (const float4*)x;

  #pragma unroll 1
  for (int s = 0; s < 8; ++s){
    const int r0 = rowbase + s*128 + w*16;       // wave's 16-row base
    const int myrow = r0 + (l & 15);
    // A loads: 2 float4 per kt, direct from global
    float4 XA[4], XB[4];
    #pragma unroll
    for (int kt = 0; kt < 4; ++kt){
      int g = kt*4 + (l >> 4);
      XA[kt] = x4[(size_t)myrow*32 + g*2];
      XB[kt] = x4[(size_t)myrow*32 + g*2 + 1];
    }
    // stats: lane-local 32-elem partial + xor16 + xor32
    float s1 = 0.f, s2 = 0.f;
    #pragma unroll
    for (int kt = 0; kt < 4; ++kt){
      s1 += XA[kt].x + XA[kt].y + XA[kt].z + XA[kt].w
          + XB[kt].x + XB[kt].y + XB[kt].z + XB[kt].w;
      s2 += XA[kt].x*XA[kt].x + XA[kt].y*XA[kt].y + XA[kt].z*XA[kt].z + XA[kt].w*XA[kt].w
          + XB[kt].x*XB[kt].x + XB[kt].y*XB[kt].y + XB[kt].z*XB[kt].z + XB[kt].w*XB[kt].w;
    }
    s1 += __shfl_xor(s1, 16); s2 += __shfl_xor(s2, 16);
    s1 += __shfl_xor(s1, 32); s2 += __shfl_xor(s2, 32);
    {
      float m = s1 * 0.0078125f;
      float var = s2 * 0.0078125f - m*m;
      float rstd = rsqrtf(var + 1e-5f);
      if (l < 16){ sMR[w*32 + l] = m; sMR[w*32 + 16 + l] = rstd; }
    }
    // pack A fragments to bf16 in-register
    uint4 af[4];
    #pragma unroll
    for (int kt = 0; kt < 4; ++kt){
      af[kt].x = bfr(XA[kt].x) | (bfr(XA[kt].y) << 16);
      af[kt].y = bfr(XA[kt].z) | (bfr(XA[kt].w) << 16);
      af[kt].z = bfr(XB[kt].x) | (bfr(XB[kt].y) << 16);
      af[kt].w = bfr(XB[kt].z) | (bfr(XB[kt].w) << 16);
    }
    // MFMA: 8 col-tiles x 4 k-granules
    f32x4 acc[8];
    #pragma unroll
    for (int c_ = 0; c_ < 8; ++c_) acc[c_] = (f32x4){0.f,0.f,0.f,0.f};
    #pragma unroll
    for (int ct = 0; ct < 8; ++ct){
      uint4 bf[4];
      #pragma unroll
      for (int kt = 0; kt < 4; ++kt){
        int wr = ct*16 + (l & 15);
        int g = kt*4 + (l >> 4);
        bf[kt] = *(const uint4*)&sWg[wr*128 + ((g ^ (wr & 7)) << 3)];
      }
      #pragma unroll
      for (int kt = 0; kt < 4; ++kt)
        acc[ct] = __builtin_amdgcn_mfma_f32_16x16x32_bf16(
            __builtin_bit_cast(bf16x8, af[kt]),
            __builtin_bit_cast(bf16x8, bf[kt]),
            acc[ct], 0, 0, 0);
    }
    // epilogue: per-row affine + wave-private repack + coalesced stores
    float mvp[4], rvp[4];
    #pragma unroll
    for (int r = 0; r < 4; ++r){
      int rl = (l >> 4)*4 + r;
      mvp[r] = sMR[w*32 + rl];
      rvp[r] = sMR[w*32 + 16 + rl];
    }
    #pragma unroll
    for (int ct = 0; ct < 8; ++ct){
      int col = ct*16 + (l & 15);
      float c1v = sC1[col], c2v = sC2[col];
      #pragma unroll
      for (int r = 0; r < 4; ++r){
        int rl = (l >> 4)*4 + r;
        float valf = rvp[r]*(acc[ct][r] - mvp[r]*c1v) + c2v;
        int gran = (col >> 3) ^ (rl & 7);
        sE[w*2048 + rl*128 + (gran << 3) + (col & 7)] = (u16)bfr(valf);
      }
    }
    uint4* dst4 = (uint4*)dstbuf;
    #pragma unroll
    for (int p = 0; p < 4; ++p){
      int fl = l + p*64;
      int nl = fl >> 4, gb = fl & 15;
      uint4 v = *(const uint4*)&sE[w*2048 + nl*128 + ((gb ^ (nl & 7)) << 3)];
      dst4[(size_t)(r0 + nl)*16 + gb] = v;
    }
  }
}

// ---------------- kernel B: q = LN(slots)@Wq^T*scale; stream k,v; partial upd/rowsum ----------------
__global__ __launch_bounds__(256) void kB(const float* __restrict__ slots,
   const u16* __restrict__ kbuf, const u16* __restrict__ vbuf,
   const float* __restrict__ Wq, const float* __restrict__ lng, const float* __restrict__ lnb,
   float* __restrict__ part, float* __restrict__ attn_out, int write_attn)
{
  const int t = threadIdx.x;
  const int b = blockIdx.x >> 3, chunk = blockIdx.x & 7;
  const int wid = t >> 6, lane = t & 63;
  const int k8 = t >> 5, q32 = t & 31;
  __shared__ __align__(16) float sSn[8*128];
  __shared__ __align__(16) float sQ[8*128];
  __shared__ __align__(16) u64 sKT[32*64];
  __shared__ __align__(16) u16 sV[64*136];
  __shared__ float sDots[8*64];
  __shared__ float sAttn[8*64];

  // s_n = LN(slots[b]) with ln_sl
  {
    float4 sv = ((const float4*)slots)[b*256 + t];
    float s  = sv.x + sv.y + sv.z + sv.w;
    float ss = sv.x*sv.x + sv.y*sv.y + sv.z*sv.z + sv.w*sv.w;
    s = red32(s); ss = red32(ss);
    float m = s*0.0078125f, var = ss*0.0078125f - m*m;
    float rstd = rsqrtf(var + 1e-5f);
    float4 gv = ((const float4*)lng)[q32], bv = ((const float4*)lnb)[q32];
    float4 sn;
    sn.x = (sv.x - m)*rstd*gv.x + bv.x;
    sn.y = (sv.y - m)*rstd*gv.y + bv.y;
    sn.z = (sv.z - m)*rstd*gv.z + bv.z;
    sn.w = (sv.w - m)*rstd*gv.w + bv.w;
    *(float4*)&sSn[t*4] = sn;
  }
  __syncthreads();
  // q[k][e] (scale folded in)
  {
    const float4* Wq4 = (const float4*)Wq;
    #pragma unroll
    for (int i = 0; i < 4; ++i){
      int e = i*32 + q32;
      float acc = 0.f;
      #pragma unroll
      for (int d4 = 0; d4 < 32; ++d4){
        float4 qs = *(const float4*)&sSn[k8*128 + d4*4];
        float4 wv = Wq4[e*32 + d4];
        acc = fmaf(qs.x,wv.x,acc); acc = fmaf(qs.y,wv.y,acc);
        acc = fmaf(qs.z,wv.z,acc); acc = fmaf(qs.w,wv.w,acc);
      }
      sQ[k8*128 + e] = acc * 0.08838834764831845f;
    }
  }
  __syncthreads();

  float ua0=0.f, ua1=0.f, ua2=0.f, ua3=0.f;
  float rsacc[8] = {0,0,0,0,0,0,0,0};
  const int dk0 = wid*2, dk1 = wid*2 + 1;

  for (int tile = 0; tile < 8; ++tile){
    const int n0 = chunk*512 + tile*64;
    const uint4* kg = (const uint4*)(kbuf + (size_t)(b*4096 + n0)*128);
    const uint4* vg = (const uint4*)(vbuf + (size_t)(b*4096 + n0)*128);
    #pragma unroll
    for (int p = 0; p < 4; ++p){
      int fl = t + p*256;
      int nl = fl >> 4, gb = fl & 15;
      uint4 kvv = kg[fl];
      int g0 = gb*2;
      sKT[g0*64 + (nl ^ (g0 & 15))]         = ((u64)kvv.y << 32) | (u64)kvv.x;
      sKT[(g0+1)*64 + (nl ^ ((g0+1) & 15))] = ((u64)kvv.w << 32) | (u64)kvv.z;
      uint4 vvv = vg[fl];
      *(uint4*)&sV[nl*136 + gb*8] = vvv;
    }
    __syncthreads();
    // dots: wave w -> slots 2w, 2w+1; lane = n
    {
      float a0 = 0.f, a1 = 0.f;
      #pragma unroll
      for (int g = 0; g < 32; ++g){
        u64 kk = sKT[g*64 + (lane ^ (g & 15))];
        u32 w0 = (u32)kk, w1 = (u32)(kk >> 32);
        float f0 = bfl(w0), f1 = bfh(w0), f2 = bfl(w1), f3 = bfh(w1);
        float4 q0 = *(const float4*)&sQ[dk0*128 + g*4];
        float4 q1 = *(const float4*)&sQ[dk1*128 + g*4];
        a0 = fmaf(f0,q0.x,a0); a0 = fmaf(f1,q0.y,a0); a0 = fmaf(f2,q0.z,a0); a0 = fmaf(f3,q0.w,a0);
        a1 = fmaf(f0,q1.x,a1); a1 = fmaf(f1,q1.y,a1); a1 = fmaf(f2,q1.z,a1); a1 = fmaf(f3,q1.w,a1);
      }
      sDots[dk0*64 + lane] = a0;
      sDots[dk1*64 + lane] = a1;
    }
    __syncthreads();
    if (t < 64){
      float dv[8], ev[8];
      #pragma unroll
      for (int j = 0; j < 8; ++j) dv[j] = sDots[j*64 + t];
      float mx = dv[0];
      #pragma unroll
      for (int j = 1; j < 8; ++j) mx = fmaxf(mx, dv[j]);
      float sum = 0.f;
      #pragma unroll
      for (int j = 0; j < 8; ++j){ ev[j] = expf(dv[j] - mx); sum += ev[j]; }
      float inv = 1.f/sum;
      #pragma unroll
      for (int j = 0; j < 8; ++j){
        float aa = ev[j]*inv;
        sAttn[j*64 + t] = aa;
        rsacc[j] += aa;
        if (write_attn) attn_out[(size_t)(b*8 + j)*4096 + n0 + t] = aa;
      }
    }
    __syncthreads();
    // updates: thread (k8, q32*4)
    #pragma unroll 8
    for (int n = 0; n < 64; ++n){
      float a = sAttn[k8*64 + n];
      u64 vv = *(const u64*)&sV[n*136 + q32*4];
      u32 w0 = (u32)vv, w1 = (u32)(vv >> 32);
      ua0 = fmaf(a, bfl(w0), ua0);
      ua1 = fmaf(a, bfh(w0), ua1);
      ua2 = fmaf(a, bfl(w1), ua2);
      ua3 = fmaf(a, bfh(w1), ua3);
    }
    __syncthreads();
  }
  float* pb = part + (size_t)blockIdx.x*1040;
  *(float4*)&pb[t*4] = make_float4(ua0, ua1, ua2, ua3);
  if (wid == 0){
    #pragma unroll
    for (int j = 0; j < 8; ++j){
      float v = rsacc[j];
      v += __shfl_xor(v,1); v += __shfl_xor(v,2); v += __shfl_xor(v,4);
      v += __shfl_xor(v,8); v += __shfl_xor(v,16); v += __shfl_xor(v,32);
      if (lane == 0) pb[1024 + j] = v;
    }
  }
}

// ---------------- kernel C: one block per slot-row; coalesced transposed-weight streams ----------------
// grid 512 = (b,k); block 384 threads.
__global__ __launch_bounds__(384) void kC(const float* __restrict__ part,
  float* __restrict__ slots, const float2* __restrict__ gruT,
  const float* __restrict__ bih, const float* __restrict__ bhh,
  const float* __restrict__ lng, const float* __restrict__ lnb,
  const float* __restrict__ w1T, const float* __restrict__ b1,
  const float* __restrict__ w2T, const float* __restrict__ b2,
  float* __restrict__ out_slots, int last)
{
  const int t = threadIdx.x;
  const int r = blockIdx.x, b = r >> 3, k = r & 7;
  __shared__ float sU[128], sS[128], sG1[384], sG2[384];
  __shared__ float sNew[128], sH[128], sH1[256];
  __shared__ float sP[4];

  // phase 0: reduce partial updates -> U; load S
  if (t < 128){
    float rs = 1e-8f;
    #pragma unroll
    for (int c = 0; c < 8; ++c) rs += part[(size_t)(b*8 + c)*1040 + 1024 + k];
    float u = 0.f;
    #pragma unroll
    for (int c = 0; c < 8; ++c) u += part[(size_t)(b*8 + c)*1040 + k*128 + t];
    sU[t] = u / rs;
    sS[t] = slots[r*128 + t];
  }
  __syncthreads();

  // phase 1: GRU gate dots (thread g owns gate g)
  {
    float acc1 = bih[t], acc2 = bhh[t];
    #pragma unroll 8
    for (int d = 0; d < 128; ++d){
      float2 w = gruT[d*384 + t];
      float ud = sU[d], sd = sS[d];
      acc1 = fmaf(ud, w.x, acc1);
      acc2 = fmaf(sd, w.y, acc2);
    }
    sG1[t] = acc1; sG2[t] = acc2;
  }
  __syncthreads();

  // phase 2: combine gates -> new slots (pre-MLP)
  if (t < 128){
    float rr = 1.f/(1.f + expf(-(sG1[t] + sG2[t])));
    float zz = 1.f/(1.f + expf(-(sG1[128 + t] + sG2[128 + t])));
    float nn = tanhf(sG1[256 + t] + rr*sG2[256 + t]);
    sNew[t] = (1.f - zz)*nn + zz*sS[t];
  }
  __syncthreads();
  // LN over sNew (threads 0..127, 2 waves -> LDS partials)
  if (t < 128){
    float v = sNew[t];
    float s = v, ss = v*v;
    s  += __shfl_xor(s,1);  ss += __shfl_xor(ss,1);
    s  += __shfl_xor(s,2);  ss += __shfl_xor(ss,2);
    s  += __shfl_xor(s,4);  ss += __shfl_xor(ss,4);
    s  += __shfl_xor(s,8);  ss += __shfl_xor(ss,8);
    s  += __shfl_xor(s,16); ss += __shfl_xor(ss,16);
    s  += __shfl_xor(s,32); ss += __shfl_xor(ss,32);
    if ((t & 63) == 0){ sP[(t >> 6)*2] = s; sP[(t >> 6)*2 + 1] = ss; }
  }
  __syncthreads();
  if (t < 128){
    float s = sP[0] + sP[2], ss = sP[1] + sP[3];
    float m = s*0.0078125f, var = ss*0.0078125f - m*m;
    float rstd = rsqrtf(var + 1e-5f);
    sH[t] = (sNew[t] - m)*rstd*lng[t] + lnb[t];
  }
  __syncthreads();

  // phase 3: MLP layer 1 + exact GELU (thread h owns neuron h, h<256)
  if (t < 256){
    float acc = b1[t];
    #pragma unroll 8
    for (int d = 0; d < 128; ++d)
      acc = fmaf(sH[d], w1T[d*256 + t], acc);
    sH1[t] = 0.5f*acc*(1.f + erff(acc*0.70710678118654752f));
  }
  __syncthreads();

  // phase 4: MLP layer 2 + residual; write back
  if (t < 128){
    float acc = b2[t];
    #pragma unroll 8
    for (int j = 0; j < 256; ++j)
      acc = fmaf(sH1[j], w2T[j*128 + t], acc);
    float res = sNew[t] + acc;
    slots[r*128 + t] = res;
    if (last) out_slots[r*128 + t] = res;
  }
}

extern "C" void kernel_launch(void* const* d_in, const int* in_sizes, int n_in,
                              void* d_out, int out_size, void* d_ws, size_t ws_size,
                              hipStream_t stream)
{
  const float* inputs   = (const float*)d_in[0];
  const float* noise    = (const float*)d_in[1];
  const float* ln_in_g  = (const float*)d_in[2];
  const float* ln_in_b  = (const float*)d_in[3];
  const float* ln_sl_g  = (const float*)d_in[4];
  const float* ln_sl_b  = (const float*)d_in[5];
  const float* ln_mlp_g = (const float*)d_in[6];
  const float* ln_mlp_b = (const float*)d_in[7];
  const float* slots_mu = (const float*)d_in[8];
  const float* slots_ls = (const float*)d_in[9];
  const float* Wq  = (const float*)d_in[10];
  const float* Wk  = (const float*)d_in[11];
  const float* Wv  = (const float*)d_in[12];
  const float* Wih = (const float*)d_in[13];
  const float* Whh = (const float*)d_in[14];
  const float* bih = (const float*)d_in[15];
  const float* bhh = (const float*)d_in[16];
  const float* W1  = (const float*)d_in[17];
  const float* b1  = (const float*)d_in[18];
  const float* W2  = (const float*)d_in[19];
  const float* b2  = (const float*)d_in[20];
  float* out = (float*)d_out;

  char* ws = (char*)d_ws;
  u16*   kbuf  = (u16*)ws;                       // 67,108,864 B
  u16*   vbuf  = (u16*)(ws + 67108864);          // 67,108,864 B
  float* slots = (float*)(ws + 134217728);       // 262,144 B
  u16*   wg    = (u16*)(ws + 134479872);         // 65,536 B
  float* c1    = (float*)(ws + 134545408);       // 1,024 B
  float* c2    = (float*)(ws + 134546432);       // 1,024 B
  float* part  = (float*)(ws + 134547456);       // 2,129,920 B
  float2* gruT = (float2*)(ws + 136677376);      // 393,216 B
  float* w1T   = (float*)(ws + 137070592);       // 131,072 B
  float* w2T   = (float*)(ws + 137201664);       // 131,072 B  (end 137,332,736)

  kInitSlots<<<64, 256, 0, stream>>>(noise, slots_mu, slots_ls, slots);
  kInitW<<<1, 256, 0, stream>>>(Wk, Wv, ln_in_g, ln_in_b, wg, c1, c2);
  kInitT<<<448, 256, 0, stream>>>(Wih, Whh, W1, W2, gruT, w1T, w2T);
  kA<<<512, 512, 0, stream>>>(inputs, wg, c1, c2, kbuf, vbuf);
  for (int it = 0; it < 3; ++it){
    kB<<<512, 256, 0, stream>>>(slots, kbuf, vbuf, Wq, ln_sl_g, ln_sl_b,
                                part, out + 65536, it == 2);
    kC<<<512, 384, 0, stream>>>(part, slots, gruT, bih, bhh,
                                ln_mlp_g, ln_mlp_b, w1T, b1, w2T, b2, out, it == 2);
  }
}

// Round 7
// 422.232 us; speedup vs baseline: 1.6287x; 1.6287x over previous
//
#include <hip/hip_runtime.h>
#include <hip/hip_bf16.h>
#include <math.h>

typedef unsigned int u32;
typedef unsigned long long u64;
typedef unsigned short u16;
typedef __bf16 bf16x8 __attribute__((ext_vector_type(8)));
typedef float f32x4 __attribute__((ext_vector_type(4)));

#define DEV __device__ __forceinline__

DEV u32 bfr(float f){ u32 u = __float_as_uint(f); return (u + 0x7fffu + ((u>>16)&1u)) >> 16; }
DEV float bfl(u32 w){ return __uint_as_float(w << 16); }
DEV float bfh(u32 w){ return __uint_as_float(w & 0xffff0000u); }
DEV float red32(float v){
  v += __shfl_xor(v,1); v += __shfl_xor(v,2); v += __shfl_xor(v,4);
  v += __shfl_xor(v,8); v += __shfl_xor(v,16); return v;
}

// ---------------- init: slots = mu + exp(ls)*noise ----------------
__global__ void kInitSlots(const float* __restrict__ noise, const float* __restrict__ mu,
                           const float* __restrict__ ls, float* __restrict__ slots){
  int i4 = blockIdx.x*256 + threadIdx.x;   // float4 idx, 0..16383
  int d4 = i4 & 31;
  float4 nv = ((const float4*)noise)[i4];
  float4 mv = ((const float4*)mu)[d4];
  float4 lv = ((const float4*)ls)[d4];
  float4 r;
  r.x = mv.x + expf(lv.x)*nv.x;
  r.y = mv.y + expf(lv.y)*nv.y;
  r.z = mv.z + expf(lv.z)*nv.z;
  r.w = mv.w + expf(lv.w)*nv.w;
  ((float4*)slots)[i4] = r;
}

// ---------------- init: Wg = [Wk;Wv]*g (bf16), c1 = sum g*W, c2 = sum b*W ----------------
__global__ void kInitW(const float* __restrict__ Wk, const float* __restrict__ Wv,
                       const float* __restrict__ g, const float* __restrict__ bb,
                       u16* __restrict__ wg, float* __restrict__ c1, float* __restrict__ c2){
  int e = threadIdx.x;  // 0..255
  const float4* src = (const float4*)((e < 128) ? (Wk + e*128) : (Wv + (e-128)*128));
  float a1 = 0.f, a2 = 0.f;
  #pragma unroll
  for (int d4 = 0; d4 < 32; ++d4){
    float4 wv = src[d4];
    float4 gv = ((const float4*)g)[d4];
    float4 bv = ((const float4*)bb)[d4];
    a1 += wv.x*gv.x + wv.y*gv.y + wv.z*gv.z + wv.w*gv.w;
    a2 += wv.x*bv.x + wv.y*bv.y + wv.z*bv.z + wv.w*bv.w;
    u32 w0 = bfr(wv.x*gv.x) | (bfr(wv.y*gv.y) << 16);
    u32 w1 = bfr(wv.z*gv.z) | (bfr(wv.w*gv.w) << 16);
    *(uint2*)&wg[e*128 + d4*4] = make_uint2(w0, w1);
  }
  c1[e] = a1; c2[e] = a2;
}

// ---------------- init: transposed weight packs for kC ----------------
__global__ void kInitT(const float* __restrict__ Wih, const float* __restrict__ Whh,
                       const float* __restrict__ W1, const float* __restrict__ W2,
                       float2* __restrict__ gruT, float* __restrict__ w1T, float* __restrict__ w2T){
  int i = blockIdx.x*256 + threadIdx.x;
  if (i < 49152){
    int d = i / 384, g = i - d*384;
    gruT[i] = make_float2(Wih[g*128 + d], Whh[g*128 + d]);
  } else if (i < 81920){
    int j = i - 49152;
    int d = j >> 8, h = j & 255;
    w1T[j] = W1[h*128 + d];
  } else if (i < 114688){
    int q = i - 81920;
    int j = q >> 7, d = q & 127;
    w2T[q] = W2[d*256 + j];
  }
}

// ---------------- kernel A: fused-LN K/V projection via bf16 MFMA ----------------
// NOTE __launch_bounds__ 2nd arg behaves as MIN WORKGROUPS PER CU here (measured:
// (512,4) -> 64-VGPR cap = 8 waves/SIMD; (512,2) -> 128 cap). Use 2 -> cap 128.
//  - A-fragments loaded DIRECTLY from global f32 x, consumed per-kt (stats+pack)
//    to keep live registers low; no LDS staging of x, no barrier in main loop.
//  - Row stats distributed by __shfl (lane rl holds row rl after xor16+xor32).
//  - Each block computes K-half OR V-half of columns (sWg 32 KB); paired blocks
//    (bid, bid+8) share the same 1024-row slab on the same XCD for L2 reuse.
//  - Wave-private 16-row epilogue repack (4 KB/wave) -> 1 KB coalesced stores.
__global__ __launch_bounds__(512, 2) void kA(const float* __restrict__ x,
    const u16* __restrict__ wg, const float* __restrict__ c1g, const float* __restrict__ c2g,
    u16* __restrict__ kbuf, u16* __restrict__ vbuf)
{
  __shared__ __align__(16) u16 sWg[128*128];     // 32 KB: this half's Wg rows
  __shared__ __align__(16) u16 sE[8*16*128];     // 32 KB: per-wave epilogue buffers
  __shared__ float sC1[128], sC2[128];
  const int t = threadIdx.x, l = t & 63, w = t >> 6;
  const int bid = blockIdx.x;
  const int half = (bid >> 3) & 1;                       // 0 = K cols, 1 = V cols
  const int rowgroup = (bid & 7)*32 + (bid >> 4);        // 0..255
  const int rowbase = rowgroup * 1024;

  // stage this half's Wg rows (swizzled 16B granules: g' = g ^ (row&7))
  const uint4* wg4 = (const uint4*)wg;
  #pragma unroll
  for (int p = 0; p < 4; ++p){
    int G = t + p*512;            // 0..2047 (128 rows x 16 granules)
    int row = G >> 4, g = G & 15;
    uint4 v = wg4[(half*128 + row)*16 + g];
    *(uint4*)&sWg[row*128 + ((g ^ (row & 7)) << 3)] = v;
  }
  if (t < 128){ sC1[t] = c1g[half*128 + t]; sC2[t] = c2g[half*128 + t]; }
  __syncthreads();   // the ONLY barrier

  u16* dstbuf = half ? vbuf : kbuf;
  const float4* x4 = (const float4*)x;

  #pragma unroll 1
  for (int s = 0; s < 8; ++s){
    const int r0 = rowbase + s*128 + w*16;       // wave's 16-row base
    const int myrow = r0 + (l & 15);
    // per-kt: load 32 contiguous bytes, accumulate stats, pack to bf16, free f32
    float s1 = 0.f, s2 = 0.f;
    uint4 af[4];
    #pragma unroll
    for (int kt = 0; kt < 4; ++kt){
      int g = kt*4 + (l >> 4);
      float4 A = x4[(size_t)myrow*32 + g*2];
      float4 B = x4[(size_t)myrow*32 + g*2 + 1];
      s1 += A.x + A.y + A.z + A.w + B.x + B.y + B.z + B.w;
      s2 += A.x*A.x + A.y*A.y + A.z*A.z + A.w*A.w
          + B.x*B.x + B.y*B.y + B.z*B.z + B.w*B.w;
      af[kt].x = bfr(A.x) | (bfr(A.y) << 16);
      af[kt].y = bfr(A.z) | (bfr(A.w) << 16);
      af[kt].z = bfr(B.x) | (bfr(B.y) << 16);
      af[kt].w = bfr(B.z) | (bfr(B.w) << 16);
    }
    s1 += __shfl_xor(s1, 16); s2 += __shfl_xor(s2, 16);
    s1 += __shfl_xor(s1, 32); s2 += __shfl_xor(s2, 32);
    float m = s1 * 0.0078125f;
    float rstd = rsqrtf(s2 * 0.0078125f - m*m + 1e-5f);
    // MFMA: 8 col-tiles x 4 k-granules
    f32x4 acc[8];
    #pragma unroll
    for (int c_ = 0; c_ < 8; ++c_) acc[c_] = (f32x4){0.f,0.f,0.f,0.f};
    #pragma unroll
    for (int ct = 0; ct < 8; ++ct){
      uint4 bf[4];
      #pragma unroll
      for (int kt = 0; kt < 4; ++kt){
        int wr = ct*16 + (l & 15);
        int g = kt*4 + (l >> 4);
        bf[kt] = *(const uint4*)&sWg[wr*128 + ((g ^ (wr & 7)) << 3)];
      }
      #pragma unroll
      for (int kt = 0; kt < 4; ++kt)
        acc[ct] = __builtin_amdgcn_mfma_f32_16x16x32_bf16(
            __builtin_bit_cast(bf16x8, af[kt]),
            __builtin_bit_cast(bf16x8, bf[kt]),
            acc[ct], 0, 0, 0);
    }
    // row stats for my 4 output rows via shfl (lane rl holds row rl's stats)
    float mvp[4], rvp[4];
    #pragma unroll
    for (int r = 0; r < 4; ++r){
      int rl = (l >> 4)*4 + r;
      mvp[r] = __shfl(m, rl);
      rvp[r] = __shfl(rstd, rl);
    }
    // epilogue: per-row affine + wave-private repack + coalesced stores
    #pragma unroll
    for (int ct = 0; ct < 8; ++ct){
      int col = ct*16 + (l & 15);
      float c1v = sC1[col], c2v = sC2[col];
      #pragma unroll
      for (int r = 0; r < 4; ++r){
        int rl = (l >> 4)*4 + r;
        float valf = rvp[r]*(acc[ct][r] - mvp[r]*c1v) + c2v;
        int gran = (col >> 3) ^ (rl & 7);
        sE[w*2048 + rl*128 + (gran << 3) + (col & 7)] = (u16)bfr(valf);
      }
    }
    uint4* dst4 = (uint4*)dstbuf;
    #pragma unroll
    for (int p = 0; p < 4; ++p){
      int fl = l + p*64;
      int nl = fl >> 4, gb = fl & 15;
      uint4 v = *(const uint4*)&sE[w*2048 + nl*128 + ((gb ^ (nl & 7)) << 3)];
      dst4[(size_t)(r0 + nl)*16 + gb] = v;
    }
  }
}

// ---------------- kernel B: q = LN(slots)@Wq^T*scale; stream k,v; partial upd/rowsum ----------------
__global__ __launch_bounds__(256) void kB(const float* __restrict__ slots,
   const u16* __restrict__ kbuf, const u16* __restrict__ vbuf,
   const float* __restrict__ Wq, const float* __restrict__ lng, const float* __restrict__ lnb,
   float* __restrict__ part, float* __restrict__ attn_out, int write_attn)
{
  const int t = threadIdx.x;
  const int b = blockIdx.x >> 3, chunk = blockIdx.x & 7;
  const int wid = t >> 6, lane = t & 63;
  const int k8 = t >> 5, q32 = t & 31;
  __shared__ __align__(16) float sSn[8*128];
  __shared__ __align__(16) float sQ[8*128];
  __shared__ __align__(16) u64 sKT[32*64];
  __shared__ __align__(16) u16 sV[64*136];
  __shared__ float sDots[8*64];
  __shared__ float sAttn[8*64];

  // s_n = LN(slots[b]) with ln_sl
  {
    float4 sv = ((const float4*)slots)[b*256 + t];
    float s  = sv.x + sv.y + sv.z + sv.w;
    float ss = sv.x*sv.x + sv.y*sv.y + sv.z*sv.z + sv.w*sv.w;
    s = red32(s); ss = red32(ss);
    float m = s*0.0078125f, var = ss*0.0078125f - m*m;
    float rstd = rsqrtf(var + 1e-5f);
    float4 gv = ((const float4*)lng)[q32], bv = ((const float4*)lnb)[q32];
    float4 sn;
    sn.x = (sv.x - m)*rstd*gv.x + bv.x;
    sn.y = (sv.y - m)*rstd*gv.y + bv.y;
    sn.z = (sv.z - m)*rstd*gv.z + bv.z;
    sn.w = (sv.w - m)*rstd*gv.w + bv.w;
    *(float4*)&sSn[t*4] = sn;
  }
  __syncthreads();
  // q[k][e] (scale folded in)
  {
    const float4* Wq4 = (const float4*)Wq;
    #pragma unroll
    for (int i = 0; i < 4; ++i){
      int e = i*32 + q32;
      float acc = 0.f;
      #pragma unroll
      for (int d4 = 0; d4 < 32; ++d4){
        float4 qs = *(const float4*)&sSn[k8*128 + d4*4];
        float4 wv = Wq4[e*32 + d4];
        acc = fmaf(qs.x,wv.x,acc); acc = fmaf(qs.y,wv.y,acc);
        acc = fmaf(qs.z,wv.z,acc); acc = fmaf(qs.w,wv.w,acc);
      }
      sQ[k8*128 + e] = acc * 0.08838834764831845f;
    }
  }
  __syncthreads();

  float ua0=0.f, ua1=0.f, ua2=0.f, ua3=0.f;
  float rsacc[8] = {0,0,0,0,0,0,0,0};
  const int dk0 = wid*2, dk1 = wid*2 + 1;

  for (int tile = 0; tile < 8; ++tile){
    const int n0 = chunk*512 + tile*64;
    const uint4* kg = (const uint4*)(kbuf + (size_t)(b*4096 + n0)*128);
    const uint4* vg = (const uint4*)(vbuf + (size_t)(b*4096 + n0)*128);
    #pragma unroll
    for (int p = 0; p < 4; ++p){
      int fl = t + p*256;
      int nl = fl >> 4, gb = fl & 15;
      uint4 kvv = kg[fl];
      int g0 = gb*2;
      sKT[g0*64 + (nl ^ (g0 & 15))]         = ((u64)kvv.y << 32) | (u64)kvv.x;
      sKT[(g0+1)*64 + (nl ^ ((g0+1) & 15))] = ((u64)kvv.w << 32) | (u64)kvv.z;
      uint4 vvv = vg[fl];
      *(uint4*)&sV[nl*136 + gb*8] = vvv;
    }
    __syncthreads();
    // dots: wave w -> slots 2w, 2w+1; lane = n
    {
      float a0 = 0.f, a1 = 0.f;
      #pragma unroll
      for (int g = 0; g < 32; ++g){
        u64 kk = sKT[g*64 + (lane ^ (g & 15))];
        u32 w0 = (u32)kk, w1 = (u32)(kk >> 32);
        float f0 = bfl(w0), f1 = bfh(w0), f2 = bfl(w1), f3 = bfh(w1);
        float4 q0 = *(const float4*)&sQ[dk0*128 + g*4];
        float4 q1 = *(const float4*)&sQ[dk1*128 + g*4];
        a0 = fmaf(f0,q0.x,a0); a0 = fmaf(f1,q0.y,a0); a0 = fmaf(f2,q0.z,a0); a0 = fmaf(f3,q0.w,a0);
        a1 = fmaf(f0,q1.x,a1); a1 = fmaf(f1,q1.y,a1); a1 = fmaf(f2,q1.z,a1); a1 = fmaf(f3,q1.w,a1);
      }
      sDots[dk0*64 + lane] = a0;
      sDots[dk1*64 + lane] = a1;
    }
    __syncthreads();
    if (t < 64){
      float dv[8], ev[8];
      #pragma unroll
      for (int j = 0; j < 8; ++j) dv[j] = sDots[j*64 + t];
      float mx = dv[0];
      #pragma unroll
      for (int j = 1; j < 8; ++j) mx = fmaxf(mx, dv[j]);
      float sum = 0.f;
      #pragma unroll
      for (int j = 0; j < 8; ++j){ ev[j] = expf(dv[j] - mx); sum += ev[j]; }
      float inv = 1.f/sum;
      #pragma unroll
      for (int j = 0; j < 8; ++j){
        float aa = ev[j]*inv;
        sAttn[j*64 + t] = aa;
        rsacc[j] += aa;
        if (write_attn) attn_out[(size_t)(b*8 + j)*4096 + n0 + t] = aa;
      }
    }
    __syncthreads();
    // updates: thread (k8, q32*4)
    #pragma unroll 8
    for (int n = 0; n < 64; ++n){
      float a = sAttn[k8*64 + n];
      u64 vv = *(const u64*)&sV[n*136 + q32*4];
      u32 w0 = (u32)vv, w1 = (u32)(vv >> 32);
      ua0 = fmaf(a, bfl(w0), ua0);
      ua1 = fmaf(a, bfh(w0), ua1);
      ua2 = fmaf(a, bfl(w1), ua2);
      ua3 = fmaf(a, bfh(w1), ua3);
    }
    __syncthreads();
  }
  float* pb = part + (size_t)blockIdx.x*1040;
  *(float4*)&pb[t*4] = make_float4(ua0, ua1, ua2, ua3);
  if (wid == 0){
    #pragma unroll
    for (int j = 0; j < 8; ++j){
      float v = rsacc[j];
      v += __shfl_xor(v,1); v += __shfl_xor(v,2); v += __shfl_xor(v,4);
      v += __shfl_xor(v,8); v += __shfl_xor(v,16); v += __shfl_xor(v,32);
      if (lane == 0) pb[1024 + j] = v;
    }
  }
}

// ---------------- kernel C: one block per slot-row; coalesced transposed-weight streams ----------------
// grid 512 = (b,k); block 384 threads.
__global__ __launch_bounds__(384) void kC(const float* __restrict__ part,
  float* __restrict__ slots, const float2* __restrict__ gruT,
  const float* __restrict__ bih, const float* __restrict__ bhh,
  const float* __restrict__ lng, const float* __restrict__ lnb,
  const float* __restrict__ w1T, const float* __restrict__ b1,
  const float* __restrict__ w2T, const float* __restrict__ b2,
  float* __restrict__ out_slots, int last)
{
  const int t = threadIdx.x;
  const int r = blockIdx.x, b = r >> 3, k = r & 7;
  __shared__ float sU[128], sS[128], sG1[384], sG2[384];
  __shared__ float sNew[128], sH[128], sH1[256];
  __shared__ float sP[4];

  // phase 0: reduce partial updates -> U; load S
  if (t < 128){
    float rs = 1e-8f;
    #pragma unroll
    for (int c = 0; c < 8; ++c) rs += part[(size_t)(b*8 + c)*1040 + 1024 + k];
    float u = 0.f;
    #pragma unroll
    for (int c = 0; c < 8; ++c) u += part[(size_t)(b*8 + c)*1040 + k*128 + t];
    sU[t] = u / rs;
    sS[t] = slots[r*128 + t];
  }
  __syncthreads();

  // phase 1: GRU gate dots (thread g owns gate g)
  {
    float acc1 = bih[t], acc2 = bhh[t];
    #pragma unroll 8
    for (int d = 0; d < 128; ++d){
      float2 w = gruT[d*384 + t];
      float ud = sU[d], sd = sS[d];
      acc1 = fmaf(ud, w.x, acc1);
      acc2 = fmaf(sd, w.y, acc2);
    }
    sG1[t] = acc1; sG2[t] = acc2;
  }
  __syncthreads();

  // phase 2: combine gates -> new slots (pre-MLP)
  if (t < 128){
    float rr = 1.f/(1.f + expf(-(sG1[t] + sG2[t])));
    float zz = 1.f/(1.f + expf(-(sG1[128 + t] + sG2[128 + t])));
    float nn = tanhf(sG1[256 + t] + rr*sG2[256 + t]);
    sNew[t] = (1.f - zz)*nn + zz*sS[t];
  }
  __syncthreads();
  // LN over sNew (threads 0..127, 2 waves -> LDS partials)
  if (t < 128){
    float v = sNew[t];
    float s = v, ss = v*v;
    s  += __shfl_xor(s,1);  ss += __shfl_xor(ss,1);
    s  += __shfl_xor(s,2);  ss += __shfl_xor(ss,2);
    s  += __shfl_xor(s,4);  ss += __shfl_xor(ss,4);
    s  += __shfl_xor(s,8);  ss += __shfl_xor(ss,8);
    s  += __shfl_xor(s,16); ss += __shfl_xor(ss,16);
    s  += __shfl_xor(s,32); ss += __shfl_xor(ss,32);
    if ((t & 63) == 0){ sP[(t >> 6)*2] = s; sP[(t >> 6)*2 + 1] = ss; }
  }
  __syncthreads();
  if (t < 128){
    float s = sP[0] + sP[2], ss = sP[1] + sP[3];
    float m = s*0.0078125f, var = ss*0.0078125f - m*m;
    float rstd = rsqrtf(var + 1e-5f);
    sH[t] = (sNew[t] - m)*rstd*lng[t] + lnb[t];
  }
  __syncthreads();

  // phase 3: MLP layer 1 + exact GELU (thread h owns neuron h, h<256)
  if (t < 256){
    float acc = b1[t];
    #pragma unroll 8
    for (int d = 0; d < 128; ++d)
      acc = fmaf(sH[d], w1T[d*256 + t], acc);
    sH1[t] = 0.5f*acc*(1.f + erff(acc*0.70710678118654752f));
  }
  __syncthreads();

  // phase 4: MLP layer 2 + residual; write back
  if (t < 128){
    float acc = b2[t];
    #pragma unroll 8
    for (int j = 0; j < 256; ++j)
      acc = fmaf(sH1[j], w2T[j*128 + t], acc);
    float res = sNew[t] + acc;
    slots[r*128 + t] = res;
    if (last) out_slots[r*128 + t] = res;
  }
}

extern "C" void kernel_launch(void* const* d_in, const int* in_sizes, int n_in,
                              void* d_out, int out_size, void* d_ws, size_t ws_size,
                              hipStream_t stream)
{
  const float* inputs   = (const float*)d_in[0];
  const float* noise    = (const float*)d_in[1];
  const float* ln_in_g  = (const float*)d_in[2];
  const float* ln_in_b  = (const float*)d_in[3];
  const float* ln_sl_g  = (const float*)d_in[4];
  const float* ln_sl_b  = (const float*)d_in[5];
  const float* ln_mlp_g = (const float*)d_in[6];
  const float* ln_mlp_b = (const float*)d_in[7];
  const float* slots_mu = (const float*)d_in[8];
  const float* slots_ls = (const float*)d_in[9];
  const float* Wq  = (const float*)d_in[10];
  const float* Wk  = (const float*)d_in[11];
  const float* Wv  = (const float*)d_in[12];
  const float* Wih = (const float*)d_in[13];
  const float* Whh = (const float*)d_in[14];
  const float* bih = (const float*)d_in[15];
  const float* bhh = (const float*)d_in[16];
  const float* W1  = (const float*)d_in[17];
  const float* b1  = (const float*)d_in[18];
  const float* W2  = (const float*)d_in[19];
  const float* b2  = (const float*)d_in[20];
  float* out = (float*)d_out;

  char* ws = (char*)d_ws;
  u16*   kbuf  = (u16*)ws;                       // 67,108,864 B
  u16*   vbuf  = (u16*)(ws + 67108864);          // 67,108,864 B
  float* slots = (float*)(ws + 134217728);       // 262,144 B
  u16*   wg    = (u16*)(ws + 134479872);         // 65,536 B
  float* c1    = (float*)(ws + 134545408);       // 1,024 B
  float* c2    = (float*)(ws + 134546432);       // 1,024 B
  float* part  = (float*)(ws + 134547456);       // 2,129,920 B
  float2* gruT = (float2*)(ws + 136677376);      // 393,216 B
  float* w1T   = (float*)(ws + 137070592);       // 131,072 B
  float* w2T   = (float*)(ws + 137201664);       // 131,072 B  (end 137,332,736)

  kInitSlots<<<64, 256, 0, stream>>>(noise, slots_mu, slots_ls, slots);
  kInitW<<<1, 256, 0, stream>>>(Wk, Wv, ln_in_g, ln_in_b, wg, c1, c2);
  kInitT<<<448, 256, 0, stream>>>(Wih, Whh, W1, W2, gruT, w1T, w2T);
  kA<<<512, 512, 0, stream>>>(inputs, wg, c1, c2, kbuf, vbuf);
  for (int it = 0; it < 3; ++it){
    kB<<<512, 256, 0, stream>>>(slots, kbuf, vbuf, Wq, ln_sl_g, ln_sl_b,
                                part, out + 65536, it == 2);
    kC<<<512, 384, 0, stream>>>(part, slots, gruT, bih, bhh,
                                ln_mlp_g, ln_mlp_b, w1T, b1, w2T, b2, out, it == 2);
  }
}

// Round 8
// 339.111 us; speedup vs baseline: 2.0279x; 1.2451x over previous
//
#include <hip/hip_runtime.h>
#include <hip/hip_bf16.h>
#include <math.h>

typedef unsigned int u32;
typedef unsigned long long u64;
typedef unsigned short u16;
typedef __bf16 bf16x8 __attribute__((ext_vector_type(8)));
typedef float f32x4 __attribute__((ext_vector_type(4)));

#define DEV __device__ __forceinline__

DEV u32 bfr(float f){ u32 u = __float_as_uint(f); return (u + 0x7fffu + ((u>>16)&1u)) >> 16; }
DEV u16 b1v(float a){ return __builtin_bit_cast(u16, (__bf16)a); }
DEV u32 pk2(float a, float b){
  return (u32)__builtin_bit_cast(u16, (__bf16)a) | ((u32)__builtin_bit_cast(u16, (__bf16)b) << 16);
}
DEV float red32(float v){
  v += __shfl_xor(v,1); v += __shfl_xor(v,2); v += __shfl_xor(v,4);
  v += __shfl_xor(v,8); v += __shfl_xor(v,16); return v;
}

// ---------------- init: slots = mu + exp(ls)*noise ----------------
__global__ void kInitSlots(const float* __restrict__ noise, const float* __restrict__ mu,
                           const float* __restrict__ ls, float* __restrict__ slots){
  int i4 = blockIdx.x*256 + threadIdx.x;
  int d4 = i4 & 31;
  float4 nv = ((const float4*)noise)[i4];
  float4 mv = ((const float4*)mu)[d4];
  float4 lv = ((const float4*)ls)[d4];
  float4 r;
  r.x = mv.x + expf(lv.x)*nv.x;
  r.y = mv.y + expf(lv.y)*nv.y;
  r.z = mv.z + expf(lv.z)*nv.z;
  r.w = mv.w + expf(lv.w)*nv.w;
  ((float4*)slots)[i4] = r;
}

// ---------------- init: Wg = [Wk;Wv]*g (bf16), c1 = sum g*W, c2 = sum b*W ----------------
__global__ void kInitW(const float* __restrict__ Wk, const float* __restrict__ Wv,
                       const float* __restrict__ g, const float* __restrict__ bb,
                       u16* __restrict__ wg, float* __restrict__ c1, float* __restrict__ c2){
  int e = threadIdx.x;
  const float4* src = (const float4*)((e < 128) ? (Wk + e*128) : (Wv + (e-128)*128));
  float a1 = 0.f, a2 = 0.f;
  #pragma unroll
  for (int d4 = 0; d4 < 32; ++d4){
    float4 wv = src[d4];
    float4 gv = ((const float4*)g)[d4];
    float4 bv = ((const float4*)bb)[d4];
    a1 += wv.x*gv.x + wv.y*gv.y + wv.z*gv.z + wv.w*gv.w;
    a2 += wv.x*bv.x + wv.y*bv.y + wv.z*bv.z + wv.w*bv.w;
    u32 w0 = bfr(wv.x*gv.x) | (bfr(wv.y*gv.y) << 16);
    u32 w1 = bfr(wv.z*gv.z) | (bfr(wv.w*gv.w) << 16);
    *(uint2*)&wg[e*128 + d4*4] = make_uint2(w0, w1);
  }
  c1[e] = a1; c2[e] = a2;
}

// ---------------- init: transposed weight packs for kC ----------------
__global__ void kInitT(const float* __restrict__ Wih, const float* __restrict__ Whh,
                       const float* __restrict__ W1, const float* __restrict__ W2,
                       float2* __restrict__ gruT, float* __restrict__ w1T, float* __restrict__ w2T){
  int i = blockIdx.x*256 + threadIdx.x;
  if (i < 49152){
    int d = i / 384, g = i - d*384;
    gruT[i] = make_float2(Wih[g*128 + d], Whh[g*128 + d]);
  } else if (i < 81920){
    int j = i - 49152;
    int d = j >> 8, h = j & 255;
    w1T[j] = W1[h*128 + d];
  } else if (i < 114688){
    int q = i - 81920;
    int j = q >> 7, d = q & 127;
    w2T[q] = W2[d*256 + j];
  }
}

// ---------------- kernel A: fused-LN K/V projection via bf16 MFMA ----------------
__global__ __launch_bounds__(512, 2) void kA(const float* __restrict__ x,
    const u16* __restrict__ wg, const float* __restrict__ c1g, const float* __restrict__ c2g,
    u16* __restrict__ kbuf, u16* __restrict__ vbuf)
{
  __shared__ __align__(16) u16 sWg[128*128];     // 32 KB: this half's Wg rows
  __shared__ __align__(16) u16 sE[8*16*128];     // 32 KB: per-wave epilogue buffers
  __shared__ float sC1[128], sC2[128];
  const int t = threadIdx.x, l = t & 63, w = t >> 6;
  const int bid = blockIdx.x;
  const int half = (bid >> 3) & 1;                       // 0 = K cols, 1 = V cols
  const int rowgroup = (bid & 7)*32 + (bid >> 4);        // 0..255
  const int rowbase = rowgroup * 1024;

  const uint4* wg4 = (const uint4*)wg;
  #pragma unroll
  for (int p = 0; p < 4; ++p){
    int G = t + p*512;
    int row = G >> 4, g = G & 15;
    uint4 v = wg4[(half*128 + row)*16 + g];
    *(uint4*)&sWg[row*128 + ((g ^ (row & 7)) << 3)] = v;
  }
  if (t < 128){ sC1[t] = c1g[half*128 + t]; sC2[t] = c2g[half*128 + t]; }
  __syncthreads();   // the ONLY barrier

  u16* dstbuf = half ? vbuf : kbuf;
  const float4* x4 = (const float4*)x;

  #pragma unroll 1
  for (int s = 0; s < 8; ++s){
    const int r0 = rowbase + s*128 + w*16;
    const int myrow = r0 + (l & 15);
    float s1 = 0.f, s2 = 0.f;
    uint4 af[4];
    #pragma unroll
    for (int kt = 0; kt < 4; ++kt){
      int g = kt*4 + (l >> 4);
      float4 A = x4[(size_t)myrow*32 + g*2];
      float4 B = x4[(size_t)myrow*32 + g*2 + 1];
      s1 += A.x + A.y + A.z + A.w + B.x + B.y + B.z + B.w;
      s2 += A.x*A.x + A.y*A.y + A.z*A.z + A.w*A.w
          + B.x*B.x + B.y*B.y + B.z*B.z + B.w*B.w;
      af[kt].x = pk2(A.x, A.y);
      af[kt].y = pk2(A.z, A.w);
      af[kt].z = pk2(B.x, B.y);
      af[kt].w = pk2(B.z, B.w);
    }
    s1 += __shfl_xor(s1, 16); s2 += __shfl_xor(s2, 16);
    s1 += __shfl_xor(s1, 32); s2 += __shfl_xor(s2, 32);
    float m = s1 * 0.0078125f;
    float rstd = rsqrtf(s2 * 0.0078125f - m*m + 1e-5f);
    f32x4 acc[8];
    #pragma unroll
    for (int c_ = 0; c_ < 8; ++c_) acc[c_] = (f32x4){0.f,0.f,0.f,0.f};
    #pragma unroll
    for (int ct = 0; ct < 8; ++ct){
      uint4 bf[4];
      #pragma unroll
      for (int kt = 0; kt < 4; ++kt){
        int wr = ct*16 + (l & 15);
        int g = kt*4 + (l >> 4);
        bf[kt] = *(const uint4*)&sWg[wr*128 + ((g ^ (wr & 7)) << 3)];
      }
      #pragma unroll
      for (int kt = 0; kt < 4; ++kt)
        acc[ct] = __builtin_amdgcn_mfma_f32_16x16x32_bf16(
            __builtin_bit_cast(bf16x8, af[kt]),
            __builtin_bit_cast(bf16x8, bf[kt]),
            acc[ct], 0, 0, 0);
    }
    float mvp[4], rvp[4];
    #pragma unroll
    for (int r = 0; r < 4; ++r){
      int rl = (l >> 4)*4 + r;
      mvp[r] = __shfl(m, rl);
      rvp[r] = __shfl(rstd, rl);
    }
    #pragma unroll
    for (int ct = 0; ct < 8; ++ct){
      int col = ct*16 + (l & 15);
      float c1v = sC1[col], c2v = sC2[col];
      #pragma unroll
      for (int r = 0; r < 4; ++r){
        int rl = (l >> 4)*4 + r;
        float valf = rvp[r]*(acc[ct][r] - mvp[r]*c1v) + c2v;
        int gran = (col >> 3) ^ (rl & 7);
        sE[w*2048 + rl*128 + (gran << 3) + (col & 7)] = b1v(valf);
      }
    }
    uint4* dst4 = (uint4*)dstbuf;
    #pragma unroll
    for (int p = 0; p < 4; ++p){
      int fl = l + p*64;
      int nl = fl >> 4, gb = fl & 15;
      uint4 v = *(const uint4*)&sE[w*2048 + nl*128 + ((gb ^ (nl & 7)) << 3)];
      dst4[(size_t)(r0 + nl)*16 + gb] = v;
    }
  }
}

// ---------------- kernel B: MFMA attention iteration ----------------
// Per block (b, chunk of 512 n): q = LN(slots)@Wq^T*scale (f32 VALU, small);
// per 64-n tile: QK^T via MFMA (A = k rows direct from global, B = q bf16 frags),
// softmax in C-layout regs (shfl over 8-lane col groups), attn->bf16 -> swizzled
// sAttnB; v staged to swizzled column-major sVT; PV via MFMA with K-accumulating
// register acc across all 8 tiles. Partials layout unchanged (kC untouched).
__global__ __launch_bounds__(256) void kB(const float* __restrict__ slots,
   const u16* __restrict__ kbuf, const u16* __restrict__ vbuf,
   const float* __restrict__ Wq, const float* __restrict__ lng, const float* __restrict__ lnb,
   float* __restrict__ part, float* __restrict__ attn_out, int write_attn)
{
  const int t = threadIdx.x;
  const int b = blockIdx.x >> 3, chunk = blockIdx.x & 7;
  const int w = t >> 6, l = t & 63;
  const int k8 = t >> 5, q32 = t & 31;
  __shared__ __align__(16) float sSn[8*128];
  __shared__ __align__(16) float sQ[8*128];
  __shared__ __align__(16) u16 sVT[128*64];      // [d][n] granule-swizzled
  __shared__ __align__(16) u16 sAttnB[16*64];    // [slot][n] granule-swizzled
  __shared__ float sRsP[32];

  // s_n = LN(slots[b]) with ln_sl
  {
    float4 sv = ((const float4*)slots)[b*256 + t];
    float s  = sv.x + sv.y + sv.z + sv.w;
    float ss = sv.x*sv.x + sv.y*sv.y + sv.z*sv.z + sv.w*sv.w;
    s = red32(s); ss = red32(ss);
    float m = s*0.0078125f, var = ss*0.0078125f - m*m;
    float rstd = rsqrtf(var + 1e-5f);
    float4 gv = ((const float4*)lng)[q32], bv = ((const float4*)lnb)[q32];
    float4 sn;
    sn.x = (sv.x - m)*rstd*gv.x + bv.x;
    sn.y = (sv.y - m)*rstd*gv.y + bv.y;
    sn.z = (sv.z - m)*rstd*gv.z + bv.z;
    sn.w = (sv.w - m)*rstd*gv.w + bv.w;
    *(float4*)&sSn[t*4] = sn;
  }
  __syncthreads();
  // q[k][e] (scale folded in)
  {
    const float4* Wq4 = (const float4*)Wq;
    #pragma unroll
    for (int i = 0; i < 4; ++i){
      int e = i*32 + q32;
      float acc = 0.f;
      #pragma unroll
      for (int d4 = 0; d4 < 32; ++d4){
        float4 qs = *(const float4*)&sSn[k8*128 + d4*4];
        float4 wv = Wq4[e*32 + d4];
        acc = fmaf(qs.x,wv.x,acc); acc = fmaf(qs.y,wv.y,acc);
        acc = fmaf(qs.z,wv.z,acc); acc = fmaf(qs.w,wv.w,acc);
      }
      sQ[k8*128 + e] = acc * 0.08838834764831845f;
    }
  }
  __syncthreads();

  // q B-fragments (bf16): lane col = slot (8..15 zero), k-elems = e
  uint4 qf[4];
  {
    int slot = l & 15;
    #pragma unroll
    for (int kt = 0; kt < 4; ++kt){
      uint4 z = make_uint4(0,0,0,0);
      if (slot < 8){
        int e0 = kt*32 + (l >> 4)*8;
        float4 qa = *(const float4*)&sQ[slot*128 + e0];
        float4 qb = *(const float4*)&sQ[slot*128 + e0 + 4];
        z.x = pk2(qa.x, qa.y); z.y = pk2(qa.z, qa.w);
        z.z = pk2(qb.x, qb.y); z.w = pk2(qb.z, qb.w);
      }
      qf[kt] = z;
    }
  }

  f32x4 accPV0 = (f32x4){0.f,0.f,0.f,0.f};
  f32x4 accPV1 = (f32x4){0.f,0.f,0.f,0.f};
  float rs = 0.f;
  const int myrow = w*16 + (l & 15);
  const size_t base = (size_t)b*4096 + (size_t)chunk*512;

  // preload tile 0 k-fragments
  uint4 kf[4];
  {
    const u16* kr = kbuf + (base + myrow)*128;
    #pragma unroll
    for (int kt = 0; kt < 4; ++kt) kf[kt] = *(const uint4*)(kr + (kt*4 + (l>>4))*8);
  }

  #pragma unroll 1
  for (int tile = 0; tile < 8; ++tile){
    const int n0 = tile*64;
    // v loads for this tile (consumed after softmax -> latency hidden)
    uint4 vld[4];
    {
      const uint4* vg = (const uint4*)(vbuf + (base + n0)*128);
      #pragma unroll
      for (int p = 0; p < 4; ++p) vld[p] = vg[t + p*256];
    }
    // QK^T: C row = n-local, col = slot
    f32x4 dacc = (f32x4){0.f,0.f,0.f,0.f};
    #pragma unroll
    for (int kt = 0; kt < 4; ++kt)
      dacc = __builtin_amdgcn_mfma_f32_16x16x32_bf16(
          __builtin_bit_cast(bf16x8, kf[kt]),
          __builtin_bit_cast(bf16x8, qf[kt]), dacc, 0, 0, 0);
    // prefetch next tile's k-fragments (kf dead after QK)
    if (tile < 7){
      const u16* kr = kbuf + (base + n0 + 64 + myrow)*128;
      #pragma unroll
      for (int kt = 0; kt < 4; ++kt) kf[kt] = *(const uint4*)(kr + (kt*4 + (l>>4))*8);
    }
    // softmax over slots (cols 0..7 per row; col>=8 groups are self-contained garbage)
    float at[4];
    #pragma unroll
    for (int r = 0; r < 4; ++r){
      float d = dacc[r];
      float mx = fmaxf(d, __shfl_xor(d, 1));
      mx = fmaxf(mx, __shfl_xor(mx, 2));
      mx = fmaxf(mx, __shfl_xor(mx, 4));
      float e = expf(d - mx);
      float s = e + __shfl_xor(e, 1);
      s += __shfl_xor(s, 2);
      s += __shfl_xor(s, 4);
      at[r] = e / s;
      rs += at[r];
    }
    // attn -> bf16 -> sAttnB[slot][n] (granule ^ slot&7); 4 consecutive n per lane
    {
      int slot = l & 15;
      int nb = w*16 + (l >> 4)*4;
      u32 lo = pk2(at[0], at[1]), hi = pk2(at[2], at[3]);
      int g = (nb >> 3) ^ (slot & 7);
      *(u64*)((char*)sAttnB + slot*128 + (g << 4) + ((nb & 7) << 1)) = ((u64)hi << 32) | (u64)lo;
    }
    // stage v -> sVT[d][n] column-major, granule ^= (d&7)^(gb&7)
    #pragma unroll
    for (int p = 0; p < 4; ++p){
      int fl = t + p*256;
      int nl = fl >> 4, gb = fl & 15;
      u32 arr[4] = {vld[p].x, vld[p].y, vld[p].z, vld[p].w};
      #pragma unroll
      for (int h = 0; h < 4; ++h){
        #pragma unroll
        for (int e2 = 0; e2 < 2; ++e2){
          int e = h*2 + e2;
          int d = gb*8 + e;
          int g = (nl >> 3) ^ (d & 7) ^ (gb & 7);
          *(u16*)((char*)sVT + d*128 + (g << 4) + ((nl & 7) << 1)) =
              (u16)(e2 ? (arr[h] >> 16) : (arr[h] & 0xffffu));
        }
      }
    }
    __syncthreads();
    // PV: A = attn (row slot), B = v (col d); accumulate across tiles
    #pragma unroll
    for (int step = 0; step < 2; ++step){
      uint4 paf;
      {
        int slot = l & 15;
        int g = (step*4 + (l >> 4)) ^ (slot & 7);
        paf = *(const uint4*)((const char*)sAttnB + slot*128 + (g << 4));
      }
      #pragma unroll
      for (int ct = 0; ct < 2; ++ct){
        int d = w*32 + ct*16 + (l & 15);
        int g = (step*4 + (l >> 4)) ^ (d & 7) ^ ((d >> 3) & 7);
        uint4 pbf = *(const uint4*)((const char*)sVT + d*128 + (g << 4));
        if (ct == 0)
          accPV0 = __builtin_amdgcn_mfma_f32_16x16x32_bf16(
              __builtin_bit_cast(bf16x8, paf), __builtin_bit_cast(bf16x8, pbf), accPV0, 0,0,0);
        else
          accPV1 = __builtin_amdgcn_mfma_f32_16x16x32_bf16(
              __builtin_bit_cast(bf16x8, paf), __builtin_bit_cast(bf16x8, pbf), accPV1, 0,0,0);
      }
    }
    if (write_attn && (l & 15) < 8){
      #pragma unroll
      for (int r = 0; r < 4; ++r)
        attn_out[(size_t)(b*8 + (l & 15))*4096 + chunk*512 + n0 + w*16 + (l >> 4)*4 + r] = at[r];
    }
    __syncthreads();
  }

  float* pb = part + (size_t)blockIdx.x*1040;
  // updates partials: D row = slot (l>>4 < 2), col = d-local
  if ((l >> 4) < 2){
    #pragma unroll
    for (int r = 0; r < 4; ++r){
      int slot = (l >> 4)*4 + r;
      pb[slot*128 + w*32 + (l & 15)] = accPV0[r];
      pb[slot*128 + w*32 + 16 + (l & 15)] = accPV1[r];
    }
  }
  // rowsum per slot: reduce rows within wave, then across waves via LDS
  rs += __shfl_xor(rs, 16);
  rs += __shfl_xor(rs, 32);
  if (l < 8) sRsP[w*8 + l] = rs;
  __syncthreads();
  if (t < 8) pb[1024 + t] = sRsP[t] + sRsP[8 + t] + sRsP[16 + t] + sRsP[24 + t];
}

// ---------------- kernel C: one block per slot-row; coalesced transposed-weight streams ----------------
__global__ __launch_bounds__(384) void kC(const float* __restrict__ part,
  float* __restrict__ slots, const float2* __restrict__ gruT,
  const float* __restrict__ bih, const float* __restrict__ bhh,
  const float* __restrict__ lng, const float* __restrict__ lnb,
  const float* __restrict__ w1T, const float* __restrict__ b1,
  const float* __restrict__ w2T, const float* __restrict__ b2,
  float* __restrict__ out_slots, int last)
{
  const int t = threadIdx.x;
  const int r = blockIdx.x, b = r >> 3, k = r & 7;
  __shared__ float sU[128], sS[128], sG1[384], sG2[384];
  __shared__ float sNew[128], sH[128], sH1[256];
  __shared__ float sP[4];

  if (t < 128){
    float rs = 1e-8f;
    #pragma unroll
    for (int c = 0; c < 8; ++c) rs += part[(size_t)(b*8 + c)*1040 + 1024 + k];
    float u = 0.f;
    #pragma unroll
    for (int c = 0; c < 8; ++c) u += part[(size_t)(b*8 + c)*1040 + k*128 + t];
    sU[t] = u / rs;
    sS[t] = slots[r*128 + t];
  }
  __syncthreads();

  {
    float acc1 = bih[t], acc2 = bhh[t];
    #pragma unroll 8
    for (int d = 0; d < 128; ++d){
      float2 w = gruT[d*384 + t];
      float ud = sU[d], sd = sS[d];
      acc1 = fmaf(ud, w.x, acc1);
      acc2 = fmaf(sd, w.y, acc2);
    }
    sG1[t] = acc1; sG2[t] = acc2;
  }
  __syncthreads();

  if (t < 128){
    float rr = 1.f/(1.f + expf(-(sG1[t] + sG2[t])));
    float zz = 1.f/(1.f + expf(-(sG1[128 + t] + sG2[128 + t])));
    float nn = tanhf(sG1[256 + t] + rr*sG2[256 + t]);
    sNew[t] = (1.f - zz)*nn + zz*sS[t];
  }
  __syncthreads();
  if (t < 128){
    float v = sNew[t];
    float s = v, ss = v*v;
    s  += __shfl_xor(s,1);  ss += __shfl_xor(ss,1);
    s  += __shfl_xor(s,2);  ss += __shfl_xor(ss,2);
    s  += __shfl_xor(s,4);  ss += __shfl_xor(ss,4);
    s  += __shfl_xor(s,8);  ss += __shfl_xor(ss,8);
    s  += __shfl_xor(s,16); ss += __shfl_xor(ss,16);
    s  += __shfl_xor(s,32); ss += __shfl_xor(ss,32);
    if ((t & 63) == 0){ sP[(t >> 6)*2] = s; sP[(t >> 6)*2 + 1] = ss; }
  }
  __syncthreads();
  if (t < 128){
    float s = sP[0] + sP[2], ss = sP[1] + sP[3];
    float m = s*0.0078125f, var = ss*0.0078125f - m*m;
    float rstd = rsqrtf(var + 1e-5f);
    sH[t] = (sNew[t] - m)*rstd*lng[t] + lnb[t];
  }
  __syncthreads();

  if (t < 256){
    float acc = b1[t];
    #pragma unroll 8
    for (int d = 0; d < 128; ++d)
      acc = fmaf(sH[d], w1T[d*256 + t], acc);
    sH1[t] = 0.5f*acc*(1.f + erff(acc*0.70710678118654752f));
  }
  __syncthreads();

  if (t < 128){
    float acc = b2[t];
    #pragma unroll 8
    for (int j = 0; j < 256; ++j)
      acc = fmaf(sH1[j], w2T[j*128 + t], acc);
    float res = sNew[t] + acc;
    slots[r*128 + t] = res;
    if (last) out_slots[r*128 + t] = res;
  }
}

extern "C" void kernel_launch(void* const* d_in, const int* in_sizes, int n_in,
                              void* d_out, int out_size, void* d_ws, size_t ws_size,
                              hipStream_t stream)
{
  const float* inputs   = (const float*)d_in[0];
  const float* noise    = (const float*)d_in[1];
  const float* ln_in_g  = (const float*)d_in[2];
  const float* ln_in_b  = (const float*)d_in[3];
  const float* ln_sl_g  = (const float*)d_in[4];
  const float* ln_sl_b  = (const float*)d_in[5];
  const float* ln_mlp_g = (const float*)d_in[6];
  const float* ln_mlp_b = (const float*)d_in[7];
  const float* slots_mu = (const float*)d_in[8];
  const float* slots_ls = (const float*)d_in[9];
  const float* Wq  = (const float*)d_in[10];
  const float* Wk  = (const float*)d_in[11];
  const float* Wv  = (const float*)d_in[12];
  const float* Wih = (const float*)d_in[13];
  const float* Whh = (const float*)d_in[14];
  const float* bih = (const float*)d_in[15];
  const float* bhh = (const float*)d_in[16];
  const float* W1  = (const float*)d_in[17];
  const float* b1  = (const float*)d_in[18];
  const float* W2  = (const float*)d_in[19];
  const float* b2  = (const float*)d_in[20];
  float* out = (float*)d_out;

  char* ws = (char*)d_ws;
  u16*   kbuf  = (u16*)ws;                       // 67,108,864 B
  u16*   vbuf  = (u16*)(ws + 67108864);          // 67,108,864 B
  float* slots = (float*)(ws + 134217728);       // 262,144 B
  u16*   wg    = (u16*)(ws + 134479872);         // 65,536 B
  float* c1    = (float*)(ws + 134545408);       // 1,024 B
  float* c2    = (float*)(ws + 134546432);       // 1,024 B
  float* part  = (float*)(ws + 134547456);       // 2,129,920 B
  float2* gruT = (float2*)(ws + 136677376);      // 393,216 B
  float* w1T   = (float*)(ws + 137070592);       // 131,072 B
  float* w2T   = (float*)(ws + 137201664);       // 131,072 B

  kInitSlots<<<64, 256, 0, stream>>>(noise, slots_mu, slots_ls, slots);
  kInitW<<<1, 256, 0, stream>>>(Wk, Wv, ln_in_g, ln_in_b, wg, c1, c2);
  kInitT<<<448, 256, 0, stream>>>(Wih, Whh, W1, W2, gruT, w1T, w2T);
  kA<<<512, 512, 0, stream>>>(inputs, wg, c1, c2, kbuf, vbuf);
  for (int it = 0; it < 3; ++it){
    kB<<<512, 256, 0, stream>>>(slots, kbuf, vbuf, Wq, ln_sl_g, ln_sl_b,
                                part, out + 65536, it == 2);
    kC<<<512, 384, 0, stream>>>(part, slots, gruT, bih, bhh,
                                ln_mlp_g, ln_mlp_b, w1T, b1, w2T, b2, out, it == 2);
  }
}